// Round 5
// baseline (3861.594 us; speedup 1.0000x reference)
//
#include <hip/hip_runtime.h>
#include <math.h>

#define T_STEPS 512
#define BATCH   16
#define DIM     1024
#define M_TOTAL (T_STEPS*BATCH)              // 8192
#define OUT_SEC ((size_t)M_TOTAL*DIM)        // 8388608 floats (output section)
#define BD      (BATCH*DIM)
#define NSLICE  16
#define CNT_STRIDE 32
#define TAG_UNITS ((size_t)2*BD)             // 2 slots of tagged h (uint2 each)
#define TAG_BYTES (TAG_UNITS*8)              // 256 KB

// ---------------------------------------------------------------------------
__device__ __forceinline__ float wred64(float v){
  #pragma unroll
  for (int off = 32; off >= 1; off >>= 1) v += __shfl_xor(v, off, 64);
  return v;
}

// ---------------------------------------------------------------------------
// Fused prep: blocks [0,2048) = pre GEMM (pre[t]=x@Wx^T+b -> h section slot t+1)
//             blocks [2048,4096) = entmax-1.5 gate -> output section
__global__ __launch_bounds__(256) void prep_kernel(const float* __restrict__ X,
                                                   const float* __restrict__ Wx,
                                                   const float* __restrict__ bias,
                                                   float* __restrict__ out_h,
                                                   const float* __restrict__ z,
                                                   float* __restrict__ gate_out){
  const int tid = threadIdx.x;
  if (blockIdx.x < 2048){
    // ---------------- pre GEMM (64x64 tile) ----------------
    __shared__ float a_s[64][17];
    __shared__ float w_s[64][17];
    const int bm = blockIdx.x & 127, bn = blockIdx.x >> 7;
    const int m0 = bm*64, n0 = bn*64;
    const int lr = tid >> 2, lc = (tid & 3) * 4;
    const int tx = tid & 15, ty = tid >> 4;

    float acc[4][4] = {};

    for (int k0 = 0; k0 < DIM; k0 += 16){
      float4 av = *reinterpret_cast<const float4*>(X  + (size_t)(m0+lr)*DIM + k0 + lc);
      float4 wv = *reinterpret_cast<const float4*>(Wx + (size_t)(n0+lr)*DIM + k0 + lc);
      __syncthreads();
      a_s[lr][lc+0]=av.x; a_s[lr][lc+1]=av.y; a_s[lr][lc+2]=av.z; a_s[lr][lc+3]=av.w;
      w_s[lr][lc+0]=wv.x; w_s[lr][lc+1]=wv.y; w_s[lr][lc+2]=wv.z; w_s[lr][lc+3]=wv.w;
      __syncthreads();
      #pragma unroll
      for (int k = 0; k < 16; ++k){
        float af[4], wf[4];
        #pragma unroll
        for (int i = 0; i < 4; ++i) af[i] = a_s[ty*4+i][k];
        #pragma unroll
        for (int j = 0; j < 4; ++j) wf[j] = w_s[tx*4+j][k];
        #pragma unroll
        for (int i = 0; i < 4; ++i)
          #pragma unroll
          for (int j = 0; j < 4; ++j) acc[i][j] = fmaf(af[i], wf[j], acc[i][j]);
      }
    }

    const float4 bv = *reinterpret_cast<const float4*>(bias + n0 + tx*4);
    #pragma unroll
    for (int i = 0; i < 4; ++i){
      float4 v;
      v.x = acc[i][0]+bv.x; v.y = acc[i][1]+bv.y; v.z = acc[i][2]+bv.z; v.w = acc[i][3]+bv.w;
      *reinterpret_cast<float4*>(out_h + (size_t)(m0+ty*4+i+BATCH)*DIM + n0 + tx*4) = v;
    }
  } else {
    // ---------------- entmax-1.5 gate ----------------
    const int bid  = blockIdx.x - 2048;
    const int row  = bid * 4 + (tid >> 6);
    const int lane = tid & 63;
    const float* zr = z + (size_t)row * DIM;

    float x[16];
    #pragma unroll
    for (int e = 0; e < 4; ++e){
      float4 v = *reinterpret_cast<const float4*>(zr + e*256 + lane*4);
      x[e*4+0]=v.x; x[e*4+1]=v.y; x[e*4+2]=v.z; x[e*4+3]=v.w;
    }

    float m = x[0];
    #pragma unroll
    for (int i = 1; i < 16; ++i) m = fmaxf(m, x[i]);
    #pragma unroll
    for (int off = 32; off >= 1; off >>= 1) m = fmaxf(m, __shfl_xor(m, off, 64));

    float lo = m - 1.0f, hi = m;
    for (int it = 0; it < 30; ++it){
      float mid = 0.5f*(lo + hi);
      float f = 0.f;
      #pragma unroll
      for (int i = 0; i < 16; ++i) f += fmaxf(x[i] - mid, 0.f);
      f = wred64(f);
      if (f >= 1.0f) lo = mid; else hi = mid;
    }
    float s = 0.f, kc = 0.f;
    #pragma unroll
    for (int i = 0; i < 16; ++i){ if (x[i] > lo){ s += x[i]; kc += 1.f; } }
    s = wred64(s); kc = wred64(kc);
    const float tau = (s - 1.0f) / kc;

    float p[16]; float ps = 0.f;
    #pragma unroll
    for (int i = 0; i < 16; ++i){ p[i] = sqrtf(fmaxf(x[i] - tau, 0.f)); ps += p[i]; }
    ps = wred64(ps);
    const float inv = 1.0f / (ps + 1e-10f);

    float* go = gate_out + (size_t)row * DIM;
    #pragma unroll
    for (int e = 0; e < 4; ++e){
      float4 v; v.x=p[e*4]*inv; v.y=p[e*4+1]*inv; v.z=p[e*4+2]*inv; v.w=p[e*4+3]*inv;
      *reinterpret_cast<float4*>(go + e*256 + lane*4) = v;
    }
  }
}

// ---------------------------------------------------------------------------
#define KA(v) asm volatile("" : "+v"(v.x), "+v"(v.y), "+v"(v.z), "+v"(v.w))

// Kernel C (tagged): persistent recurrence, wave-autonomous, zero barriers.
// Each (value, step-tag) travels as one 8B packet through a 2-slot ping-pong
// buffer in ws (LLC-resident, L1/L2-bypass). Readers poll the data itself:
// sync chain = writer store -> LLC -> reader poll load. No counter, no drain,
// no __syncthreads in the loop.
__global__ __launch_bounds__(512, 1) void rnn_tagged(const float* __restrict__ h0,
                                                     const float* __restrict__ Wh,
                                                     float* __restrict__ out,
                                                     uint2* __restrict__ tagbuf){
  float* out_h = out + OUT_SEC;
  const int tid  = threadIdx.x;
  const int lane = tid & 63;
  const int w    = tid >> 6;
  const int b    = blockIdx.x >> 4;     // batch 0..15
  const int s    = blockIdx.x & 15;     // slice 0..15
  const int dbase = s*64 + w*8;

  // W_h slice 8 rows x 16 cols (served from L1 if not register-resident)
  float4 wreg[8][4];
  #pragma unroll
  for (int r = 0; r < 8; ++r)
    #pragma unroll
    for (int j = 0; j < 4; ++j)
      wreg[r][j] = *reinterpret_cast<const float4*>(
          Wh + (size_t)(dbase + r)*DIM + lane*4 + j*256);

  KA(wreg[0][0]); KA(wreg[0][1]); KA(wreg[0][2]); KA(wreg[0][3]);
  KA(wreg[1][0]); KA(wreg[1][1]); KA(wreg[1][2]); KA(wreg[1][3]);
  KA(wreg[2][0]); KA(wreg[2][1]); KA(wreg[2][2]); KA(wreg[2][3]);
  KA(wreg[3][0]); KA(wreg[3][1]); KA(wreg[3][2]); KA(wreg[3][3]);
  KA(wreg[4][0]); KA(wreg[4][1]); KA(wreg[4][2]); KA(wreg[4][3]);
  KA(wreg[5][0]); KA(wreg[5][1]); KA(wreg[5][2]); KA(wreg[5][3]);
  KA(wreg[6][0]); KA(wreg[6][1]); KA(wreg[6][2]); KA(wreg[6][3]);
  KA(wreg[7][0]); KA(wreg[7][1]); KA(wreg[7][2]); KA(wreg[7][3]);

  // h[0] = h0 in the validated h section
  if (tid < 16)
    reinterpret_cast<float4*>(out_h + (size_t)b*DIM + s*64)[tid] =
        reinterpret_cast<const float4*>(h0 + (size_t)b*DIM + s*64)[tid];

  for (int t = 0; t < T_STEPS; ++t){
    // prefetch pre (h slot t+1) and gate (out slot t) — own region, cached
    float pre_v = 0.f, gate_v = 0.f;
    if (lane < 8){
      const size_t d = dbase + lane;
      pre_v  = out_h[(size_t)(t+1)*BD + (size_t)b*DIM + d];
      gate_v = out  [(size_t)t*BD     + (size_t)b*DIM + d];
    }

    float4 hv0, hv1, hv2, hv3;
    if (t == 0){
      const float* hs = h0 + (size_t)b*DIM + lane*4;
      hv0 = *reinterpret_cast<const float4*>(hs);
      hv1 = *reinterpret_cast<const float4*>(hs + 256);
      hv2 = *reinterpret_cast<const float4*>(hs + 512);
      hv3 = *reinterpret_cast<const float4*>(hs + 768);
    } else {
      // poll tagged h[t][b]: 16 (value,tag) pairs per lane
      const uint2* slot = tagbuf + (size_t)(t & 1)*BD + (size_t)b*DIM;
      const uint2* p0 = slot + lane*4;
      const uint2* p1 = p0 + 256;
      const uint2* p2 = p0 + 512;
      const uint2* p3 = p0 + 768;
      const unsigned want = (unsigned)t;
      float4 q0,q1,q2,q3,q4,q5,q6,q7;
      for (;;){
        asm volatile(
          "global_load_dwordx4 %0, %8, off sc0 sc1\n\t"
          "global_load_dwordx4 %1, %8, off offset:16 sc0 sc1\n\t"
          "global_load_dwordx4 %2, %9, off sc0 sc1\n\t"
          "global_load_dwordx4 %3, %9, off offset:16 sc0 sc1\n\t"
          "global_load_dwordx4 %4, %10, off sc0 sc1\n\t"
          "global_load_dwordx4 %5, %10, off offset:16 sc0 sc1\n\t"
          "global_load_dwordx4 %6, %11, off sc0 sc1\n\t"
          "global_load_dwordx4 %7, %11, off offset:16 sc0 sc1\n\t"
          "s_waitcnt vmcnt(0)"
          : "=&v"(q0), "=&v"(q1), "=&v"(q2), "=&v"(q3),
            "=&v"(q4), "=&v"(q5), "=&v"(q6), "=&v"(q7)
          : "v"(p0), "v"(p1), "v"(p2), "v"(p3)
          : "memory");
        unsigned ok =
          (__float_as_uint(q0.y)==want) & (__float_as_uint(q0.w)==want) &
          (__float_as_uint(q1.y)==want) & (__float_as_uint(q1.w)==want) &
          (__float_as_uint(q2.y)==want) & (__float_as_uint(q2.w)==want) &
          (__float_as_uint(q3.y)==want) & (__float_as_uint(q3.w)==want) &
          (__float_as_uint(q4.y)==want) & (__float_as_uint(q4.w)==want) &
          (__float_as_uint(q5.y)==want) & (__float_as_uint(q5.w)==want) &
          (__float_as_uint(q6.y)==want) & (__float_as_uint(q6.w)==want) &
          (__float_as_uint(q7.y)==want) & (__float_as_uint(q7.w)==want);
        if (__all((int)ok)) break;
      }
      hv0.x=q0.x; hv0.y=q0.z; hv0.z=q1.x; hv0.w=q1.z;
      hv1.x=q2.x; hv1.y=q2.z; hv1.z=q3.x; hv1.w=q3.z;
      hv2.x=q4.x; hv2.y=q4.z; hv2.z=q5.x; hv2.w=q5.z;
      hv3.x=q6.x; hv3.y=q6.z; hv3.z=q7.x; hv3.w=q7.z;
    }

    // 8 rows x 16 FMA; butterfly reduce; capture row r in lane r
    float myv = 0.f;
    #pragma unroll
    for (int r = 0; r < 8; ++r){
      float a = 0.f;
      {
        const float4 w0 = wreg[r][0], w1 = wreg[r][1],
                     w2 = wreg[r][2], w3 = wreg[r][3];
        a = fmaf(w0.x, hv0.x, fmaf(w0.y, hv0.y, fmaf(w0.z, hv0.z, fmaf(w0.w, hv0.w, a))));
        a = fmaf(w1.x, hv1.x, fmaf(w1.y, hv1.y, fmaf(w1.z, hv1.z, fmaf(w1.w, hv1.w, a))));
        a = fmaf(w2.x, hv2.x, fmaf(w2.y, hv2.y, fmaf(w2.z, hv2.z, fmaf(w2.w, hv2.w, a))));
        a = fmaf(w3.x, hv3.x, fmaf(w3.y, hv3.y, fmaf(w3.z, hv3.z, fmaf(w3.w, hv3.w, a))));
      }
      a += __shfl_xor(a, 1, 64);
      a += __shfl_xor(a, 2, 64);
      a += __shfl_xor(a, 4, 64);
      a += __shfl_xor(a, 8, 64);
      a += __shfl_xor(a, 16, 64);
      a += __shfl_xor(a, 32, 64);
      if (lane == r) myv = a;
    }

    if (lane < 8){
      const float v  = pre_v + myv;
      const float e  = __expf(2.0f * v);
      const float hn = 1.0f - 2.0f / (e + 1.0f);   // tanh(v)
      const size_t d = dbase + lane;
      // tagged packet (value, t+1) -> ping-pong slot, LLC-direct
      const unsigned long long pkt =
          ((unsigned long long)(unsigned)(t + 1) << 32) |
          (unsigned long long)__float_as_uint(hn);
      __hip_atomic_store(
          reinterpret_cast<unsigned long long*>(
              tagbuf + (size_t)((t + 1) & 1)*BD + (size_t)b*DIM + d),
          pkt, __ATOMIC_RELAXED, __HIP_MEMORY_SCOPE_AGENT);
      // validated h + output (cached; read only after kernel end)
      out_h[(size_t)(t+1)*BD + (size_t)b*DIM + d] = hn;
      out  [(size_t)t*BD     + (size_t)b*DIM + d] = hn * gate_v;
    }
  }
}

// ---------------------------------------------------------------------------
// Fallback (ws too small for tag buffer): round-4 counter-flag kernel.
__global__ __launch_bounds__(512, 1) void rnn_flag(const float* __restrict__ h0,
                                                   const float* __restrict__ Wh,
                                                   float* __restrict__ out,
                                                   unsigned* __restrict__ prog){
  float* out_h = out + OUT_SEC;
  const int tid  = threadIdx.x;
  const int lane = tid & 63;
  const int w    = tid >> 6;
  const int b    = blockIdx.x >> 4;
  const int s    = blockIdx.x & 15;
  const int dbase = s*64 + w*8;

  float4 wreg[8][4];
  #pragma unroll
  for (int r = 0; r < 8; ++r)
    #pragma unroll
    for (int j = 0; j < 4; ++j)
      wreg[r][j] = *reinterpret_cast<const float4*>(
          Wh + (size_t)(dbase + r)*DIM + lane*4 + j*256);

  if (tid < 16)
    reinterpret_cast<float4*>(out_h + (size_t)b*DIM + s*64)[tid] =
        reinterpret_cast<const float4*>(h0 + (size_t)b*DIM + s*64)[tid];

  unsigned* cnt = &prog[b * CNT_STRIDE];

  for (int t = 0; t < T_STEPS; ++t){
    float pre_v = 0.f, gate_v = 0.f;
    if (lane < 8){
      const size_t d = dbase + lane;
      pre_v  = out_h[(size_t)(t+1)*BD + (size_t)b*DIM + d];
      gate_v = out  [(size_t)t*BD     + (size_t)b*DIM + d];
    }
    if (t > 0){
      if (tid == 0){
        while (__hip_atomic_load(cnt, __ATOMIC_RELAXED, __HIP_MEMORY_SCOPE_AGENT)
               < (unsigned)(NSLICE * t)) { }
      }
      __syncthreads();
    }
    const float* hsrc = (t == 0) ? (h0 + (size_t)b*DIM)
                                 : (out_h + (size_t)t*BD + (size_t)b*DIM);
    const float* a0 = hsrc + lane*4;
    const float* a1 = a0 + 256;
    const float* a2 = a0 + 512;
    const float* a3 = a0 + 768;
    float4 hv0, hv1, hv2, hv3;
    asm volatile(
      "global_load_dwordx4 %0, %4, off sc0 sc1\n\t"
      "global_load_dwordx4 %1, %5, off sc0 sc1\n\t"
      "global_load_dwordx4 %2, %6, off sc0 sc1\n\t"
      "global_load_dwordx4 %3, %7, off sc0 sc1\n\t"
      "s_waitcnt vmcnt(0)"
      : "=&v"(hv0), "=&v"(hv1), "=&v"(hv2), "=&v"(hv3)
      : "v"(a0), "v"(a1), "v"(a2), "v"(a3)
      : "memory");

    float myv = 0.f;
    #pragma unroll
    for (int r = 0; r < 8; ++r){
      float a = 0.f;
      const float4 w0 = wreg[r][0], w1 = wreg[r][1],
                   w2 = wreg[r][2], w3 = wreg[r][3];
      a = fmaf(w0.x, hv0.x, fmaf(w0.y, hv0.y, fmaf(w0.z, hv0.z, fmaf(w0.w, hv0.w, a))));
      a = fmaf(w1.x, hv1.x, fmaf(w1.y, hv1.y, fmaf(w1.z, hv1.z, fmaf(w1.w, hv1.w, a))));
      a = fmaf(w2.x, hv2.x, fmaf(w2.y, hv2.y, fmaf(w2.z, hv2.z, fmaf(w2.w, hv2.w, a))));
      a = fmaf(w3.x, hv3.x, fmaf(w3.y, hv3.y, fmaf(w3.z, hv3.z, fmaf(w3.w, hv3.w, a))));
      a += __shfl_xor(a, 1, 64);
      a += __shfl_xor(a, 2, 64);
      a += __shfl_xor(a, 4, 64);
      a += __shfl_xor(a, 8, 64);
      a += __shfl_xor(a, 16, 64);
      a += __shfl_xor(a, 32, 64);
      if (lane == r) myv = a;
    }

    if (lane < 8){
      const float v  = pre_v + myv;
      const float e  = __expf(2.0f * v);
      const float hn = 1.0f - 2.0f / (e + 1.0f);
      const size_t d = dbase + lane;
      __hip_atomic_store(out_h + (size_t)(t+1)*BD + (size_t)b*DIM + d, hn,
                         __ATOMIC_RELAXED, __HIP_MEMORY_SCOPE_AGENT);
      out[(size_t)t*BD + (size_t)b*DIM + d] = hn * gate_v;
    }

    __syncthreads();
    if (tid == 0){
      asm volatile("s_waitcnt vmcnt(0)" ::: "memory");
      __hip_atomic_fetch_add(cnt, 1u, __ATOMIC_RELAXED, __HIP_MEMORY_SCOPE_AGENT);
    }
  }
}

// ---------------------------------------------------------------------------
extern "C" void kernel_launch(void* const* d_in, const int* in_sizes, int n_in,
                              void* d_out, int out_size, void* d_ws, size_t ws_size,
                              hipStream_t stream){
  (void)in_sizes; (void)n_in; (void)out_size;
  const float* x    = (const float*)d_in[0];
  const float* z    = (const float*)d_in[1];
  const float* h0   = (const float*)d_in[2];
  const float* Wx   = (const float*)d_in[3];
  const float* Wh   = (const float*)d_in[4];
  const float* bias = (const float*)d_in[5];
  float* out   = (float*)d_out;
  float* out_h = out + OUT_SEC;

  const bool tagged = (ws_size >= TAG_BYTES);
  hipMemsetAsync(d_ws, 0, tagged ? TAG_BYTES : (size_t)(BATCH*CNT_STRIDE*4), stream);
  prep_kernel<<<4096, 256, 0, stream>>>(x, Wx, bias, out_h, z, out);
  if (tagged)
    rnn_tagged<<<256, 512, 0, stream>>>(h0, Wh, out, (uint2*)d_ws);
  else
    rnn_flag<<<256, 512, 0, stream>>>(h0, Wh, out, (unsigned*)d_ws);
}